// Round 5
// baseline (12785.711 us; speedup 1.0000x reference)
//
#include <hip/hip_runtime.h>
#include <hip/hip_fp16.h>

// LSTM: B=128, T=500 (499 steps used), in=265 (padded 288), H=512, out=123.
// R5: dynamic placement-aware tiling. Each WG reads HW_REG_XCC_ID, publishes
// it, and (after a one-time LLC barrier) all WGs redundantly compute the
// placement histogram. If each XCD holds exactly 32 WGs, tile = XCD and
// hs = rank-within-XCD -> the whole per-step h-exchange + flag sync runs in
// the tile's own XCD L2 (sc0 ops). Otherwise ALL WGs deterministically fall
// back to the proven LLC path (sc0 sc1). Per-step sync = per-WG flag stores
// (no atomics) + one coalesced 128B flag-line poll per wave.

typedef _Float16 f16;
typedef _Float16 f16x8 __attribute__((ext_vector_type(8)));
typedef float f32x4 __attribute__((ext_vector_type(4)));

#define TS 499

// ---- ws layout (bytes) ----
#define NEWX_OFF   0ul
#define NEWX_BYTES (500ul*128*288*2)
#define HALL_OFF   (NEWX_OFF + NEWX_BYTES)
#define HALL_BYTES (500ul*128*512*2)
#define WHH_OFF    (HALL_OFF + HALL_BYTES)
#define WHH_BYTES  (2048ul*512*2)
#define WIH_OFF    (WHH_OFF + WHH_BYTES)
#define WIH_BYTES  (2048ul*288*2)
#define WFC_OFF    (WIH_OFF + WIH_BYTES)
#define WFC_BYTES  (128ul*512*2)
#define BIAS_OFF   (WFC_OFF + WFC_BYTES)
#define BIAS_BYTES (2048ul*4)
#define CNT_OFF    (BIAS_OFF + BIAS_BYTES)
// cnt u32 indices: [0] handshake arrival counter
//                  [64..319] xcd publish slots (one per WG)
//                  [512 + tile*32 + hs] per-tile step flags (128B/tile line)
#define CNT_BYTES  (4096ul)
#define WS_NEED    (CNT_OFF + CNT_BYTES)

__device__ __forceinline__ float tanh_dev(float x) {
    float ax = fabsf(x);
    float e  = __expf(-2.f * ax);
    float r  = (1.f - e) / (1.f + e);
    return copysignf(r, x);
}
__device__ __forceinline__ float sigm_dev(float x) {
    float e = __expf(-fabsf(x));
    float p = 1.f / (1.f + e);
    return x >= 0.f ? p : 1.f - p;
}

// ---- coherence helpers ----
__device__ __forceinline__ void llc_store_u32(unsigned* p, unsigned v) {
    asm volatile("global_store_dword %0, %1, off sc0 sc1\n\ts_waitcnt vmcnt(0)"
                 :: "v"(p), "v"(v) : "memory");
}
__device__ __forceinline__ void l2_store_u32(unsigned* p, unsigned v) {
    asm volatile("global_store_dword %0, %1, off sc0\n\ts_waitcnt vmcnt(0)"
                 :: "v"(p), "v"(v) : "memory");
}
__device__ __forceinline__ void llc_atomic_inc(unsigned* p) {
    unsigned one = 1u;
    asm volatile("global_atomic_add %0, %1, off sc1" :: "v"(p), "v"(one) : "memory");
}
__device__ __forceinline__ unsigned llc_load_u32(const unsigned* p) {
    unsigned v;
    asm volatile("global_load_dword %0, %1, off sc0 sc1\n\ts_waitcnt vmcnt(0)"
                 : "=v"(v) : "v"(p) : "memory");
    return v;
}
__device__ __forceinline__ unsigned l2_load_u32(const unsigned* p) {
    unsigned v;
    asm volatile("global_load_dword %0, %1, off sc0\n\ts_waitcnt vmcnt(0)"
                 : "=v"(v) : "v"(p) : "memory");
    return v;
}

// ---------------- phase 1a ----------------
__global__ void __launch_bounds__(256) prep_newx(const float* __restrict__ x,
                                                 f16* __restrict__ newx) {
    const int t   = blockIdx.x;       // 0..498
    const int b0  = blockIdx.y * 16;
    const int tid = threadIdx.x;
    for (int bb = 0; bb < 16; ++bb) {
        const int b = b0 + bb;
        const float* xr = x + ((size_t)b * 500 + t) * 248;
        const int ab = (int)xr[246];
        const int df = (int)xr[247];
        f16* orow = newx + ((size_t)t * 128 + b) * 288;
        for (int k = tid; k < 288; k += 256) {
            float v;
            if (k < 246)      v = tanh_dev(xr[k]);
            else if (k < 257) v = (k - 246 == df) ? 0.76159415595576485f : 0.f;
            else if (k < 265) v = (k - 257 == ab) ? 0.76159415595576485f : 0.f;
            else              v = 0.f;
            orow[k] = (f16)v;
        }
    }
}

// ---------------- phase 1b ----------------
__global__ void __launch_bounds__(256) prep_w(const float* __restrict__ W_ih,
                                              const float* __restrict__ W_hh,
                                              const float* __restrict__ W_fc,
                                              const float* __restrict__ b_ih,
                                              const float* __restrict__ b_hh,
                                              f16* __restrict__ whh, f16* __restrict__ wih,
                                              f16* __restrict__ wfc, float* __restrict__ bias) {
    const int NHH = 2048 * 512;
    const int NIH = 2048 * 288;
    const int NFC = 128 * 512;
    const int NT  = NHH + NIH + NFC + 2048;
    for (int i = blockIdx.x * 256 + threadIdx.x; i < NT; i += gridDim.x * 256) {
        if (i < NHH) {
            whh[i] = (f16)W_hh[i];
        } else if (i < NHH + NIH) {
            int j2 = i - NHH; int rr = j2 / 288, kk = j2 % 288;
            wih[j2] = (kk < 265) ? (f16)W_ih[rr * 265 + kk] : (f16)0.f;
        } else if (i < NHH + NIH + NFC) {
            int j2 = i - (NHH + NIH); int rr = j2 >> 9, kk = j2 & 511;
            wfc[j2] = (rr < 123) ? (f16)W_fc[rr * 512 + kk] : (f16)0.f;
        } else {
            int j2 = i - (NHH + NIH + NFC);
            bias[j2] = b_ih[j2] + b_hh[j2];
        }
    }
}

// h-load asm: 16 x dwordx4 + internal vmcnt (consumers have data deps on outputs)
#define HLOAD_ASM(FLAGS)                                                      \
    asm volatile(                                                             \
        "global_load_dwordx4 %0,  %16, off " FLAGS "\n\t"                     \
        "global_load_dwordx4 %1,  %16, off offset:64 " FLAGS "\n\t"           \
        "global_load_dwordx4 %2,  %16, off offset:128 " FLAGS "\n\t"          \
        "global_load_dwordx4 %3,  %16, off offset:192 " FLAGS "\n\t"          \
        "global_load_dwordx4 %4,  %16, off offset:256 " FLAGS "\n\t"          \
        "global_load_dwordx4 %5,  %16, off offset:320 " FLAGS "\n\t"          \
        "global_load_dwordx4 %6,  %16, off offset:384 " FLAGS "\n\t"          \
        "global_load_dwordx4 %7,  %16, off offset:448 " FLAGS "\n\t"          \
        "global_load_dwordx4 %8,  %16, off offset:512 " FLAGS "\n\t"          \
        "global_load_dwordx4 %9,  %16, off offset:576 " FLAGS "\n\t"          \
        "global_load_dwordx4 %10, %16, off offset:640 " FLAGS "\n\t"          \
        "global_load_dwordx4 %11, %16, off offset:704 " FLAGS "\n\t"          \
        "global_load_dwordx4 %12, %16, off offset:768 " FLAGS "\n\t"          \
        "global_load_dwordx4 %13, %16, off offset:832 " FLAGS "\n\t"          \
        "global_load_dwordx4 %14, %16, off offset:896 " FLAGS "\n\t"          \
        "global_load_dwordx4 %15, %16, off offset:960 " FLAGS "\n\t"          \
        "s_waitcnt vmcnt(0)"                                                  \
        : "=&v"(h00), "=&v"(h01), "=&v"(h02), "=&v"(h03),                     \
          "=&v"(h04), "=&v"(h05), "=&v"(h06), "=&v"(h07),                     \
          "=&v"(h08), "=&v"(h09), "=&v"(h10), "=&v"(h11),                     \
          "=&v"(h12), "=&v"(h13), "=&v"(h14), "=&v"(h15)                      \
        : "v"(hp)                                                             \
        : "memory")

// ---------------- phase 2 main loop (templated on sync scope) ----------------
template <int UNI>
__device__ __forceinline__ void lstm_loop(const f16* __restrict__ newx,
                                          f16* __restrict__ hall,
                                          unsigned* flags,
                                          const f16x8 (&wh)[16], const f16x8 (&wi)[9],
                                          float bb, int btile, int hs, int tid,
                                          float* gf) {
    const int wl = tid & 63;
    const int arow = wl & 15, kgrp = wl >> 4;
    const int l = tid >> 2, r = tid & 3;
    const int jcol = l & 15, irow = ((l >> 4) << 2) + r;
    const int abase = btile * 16 + arow;
    float c_st = 0.f;

    f16x8 xa[9];
    {
        const f16* q = newx + (size_t)abase * 288 + kgrp * 8;
        #pragma unroll
        for (int kc = 0; kc < 9; ++kc) xa[kc] = *(const f16x8*)(q + kc * 32);
    }

    unsigned* const myflag = flags + hs;
    const unsigned* const pfl = flags + (wl & 31);   // lanes 0..31 poll the line

    for (int t = 0; t < TS; ++t) {
        f32x4 acc = {bb, bb, bb, bb};
        #pragma unroll
        for (int kc = 0; kc < 9; ++kc)
            acc = __builtin_amdgcn_mfma_f32_16x16x32_f16(xa[kc], wi[kc], acc, 0, 0, 0);
        // prefetch next step's x fragments (in flight during the poll)
        {
            const f16* q = newx + ((size_t)(t + 1) * 128 + abase) * 288 + kgrp * 8;
            #pragma unroll
            for (int kc = 0; kc < 9; ++kc) xa[kc] = *(const f16x8*)(q + kc * 32);
        }

        if (t > 0) {
            // every wave polls: one coalesced 128B flag-line load + ballot
            int spins = 0;
            for (;;) {
                unsigned f = 0xFFFFFFFFu;
                if (wl < 32) f = UNI ? l2_load_u32(pfl) : llc_load_u32(pfl);
                if (__ballot(f >= (unsigned)t) == ~0ull) break;
                __builtin_amdgcn_s_sleep(1);
                if (++spins > (1 << 14)) break;   // degrade, never hang
            }
            const f16* hp = hall + ((size_t)(t - 1) * 128 + abase) * 512 + kgrp * 8;
            f16x8 h00,h01,h02,h03,h04,h05,h06,h07,h08,h09,h10,h11,h12,h13,h14,h15;
            if constexpr (UNI) HLOAD_ASM("sc0");
            else               HLOAD_ASM("sc0 sc1");
            f32x4 e0 = {0.f,0.f,0.f,0.f}, e1 = {0.f,0.f,0.f,0.f};
            e0 = __builtin_amdgcn_mfma_f32_16x16x32_f16(h00, wh[0],  e0, 0, 0, 0);
            e1 = __builtin_amdgcn_mfma_f32_16x16x32_f16(h01, wh[1],  e1, 0, 0, 0);
            e0 = __builtin_amdgcn_mfma_f32_16x16x32_f16(h02, wh[2],  e0, 0, 0, 0);
            e1 = __builtin_amdgcn_mfma_f32_16x16x32_f16(h03, wh[3],  e1, 0, 0, 0);
            e0 = __builtin_amdgcn_mfma_f32_16x16x32_f16(h04, wh[4],  e0, 0, 0, 0);
            e1 = __builtin_amdgcn_mfma_f32_16x16x32_f16(h05, wh[5],  e1, 0, 0, 0);
            e0 = __builtin_amdgcn_mfma_f32_16x16x32_f16(h06, wh[6],  e0, 0, 0, 0);
            e1 = __builtin_amdgcn_mfma_f32_16x16x32_f16(h07, wh[7],  e1, 0, 0, 0);
            e0 = __builtin_amdgcn_mfma_f32_16x16x32_f16(h08, wh[8],  e0, 0, 0, 0);
            e1 = __builtin_amdgcn_mfma_f32_16x16x32_f16(h09, wh[9],  e1, 0, 0, 0);
            e0 = __builtin_amdgcn_mfma_f32_16x16x32_f16(h10, wh[10], e0, 0, 0, 0);
            e1 = __builtin_amdgcn_mfma_f32_16x16x32_f16(h11, wh[11], e1, 0, 0, 0);
            e0 = __builtin_amdgcn_mfma_f32_16x16x32_f16(h12, wh[12], e0, 0, 0, 0);
            e1 = __builtin_amdgcn_mfma_f32_16x16x32_f16(h13, wh[13], e1, 0, 0, 0);
            e0 = __builtin_amdgcn_mfma_f32_16x16x32_f16(h14, wh[14], e0, 0, 0, 0);
            e1 = __builtin_amdgcn_mfma_f32_16x16x32_f16(h15, wh[15], e1, 0, 0, 0);
            acc += e0; acc += e1;
        }

        // gate exchange through LDS
        *(f32x4*)(gf + tid * 4) = acc;
        __syncthreads();
        float iv = sigm_dev(gf[tid]);
        float fv = sigm_dev(gf[256 + tid]);
        float gv = tanh_dev(gf[512 + tid]);
        float ov = sigm_dev(gf[768 + tid]);
        c_st = fv * c_st + iv * gv;
        float hv = ov * tanh_dev(c_st);

        {
            f16 hv16 = (f16)hv;
            unsigned u32v = (unsigned)__builtin_bit_cast(unsigned short, hv16);
            const f16* sp = hall + ((size_t)t * 128 + btile * 16 + irow) * 512 + hs * 16 + jcol;
            if constexpr (UNI)
                asm volatile("global_store_short %0, %1, off sc0" :: "v"(sp), "v"(u32v) : "memory");
            else
                asm volatile("global_store_short %0, %1, off sc0 sc1" :: "v"(sp), "v"(u32v) : "memory");
        }
        asm volatile("s_waitcnt vmcnt(0)" ::: "memory");   // h committed at coherence point
        __syncthreads();                                    // all 4 waves' h stores done
        if (tid == 0) {
            if constexpr (UNI) l2_store_u32(myflag, (unsigned)(t + 1));
            else               llc_store_u32(myflag, (unsigned)(t + 1));
        }
    }
}

__global__ void __launch_bounds__(256, 1) lstm_seq(const f16* __restrict__ newx,
                                                   f16* __restrict__ hall,
                                                   const f16* __restrict__ whh,
                                                   const f16* __restrict__ wih,
                                                   const float* __restrict__ bias,
                                                   unsigned* __restrict__ cnt) {
    __shared__ float gf[1024];
    __shared__ unsigned ldsx[256];
    const int tid = threadIdx.x;
    const int bid = blockIdx.x;

    unsigned xcd;
    asm volatile("s_getreg_b32 %0, hwreg(HW_REG_XCC_ID)" : "=s"(xcd));

    unsigned* hcnt = cnt;          // [0]
    unsigned* xcds = cnt + 64;     // [64..319]

    // --- one-time placement handshake (LLC) ---
    if (tid == 0) {
        llc_store_u32(&xcds[bid], xcd);   // committed before the arrive below
        llc_atomic_inc(hcnt);
        int spins = 0;
        while (llc_load_u32(hcnt) < 256u) {
            __builtin_amdgcn_s_sleep(8);
            if (++spins > (1 << 20)) break;   // degrade, never hang
        }
    }
    __syncthreads();
    ldsx[tid] = llc_load_u32(&xcds[tid]);
    __syncthreads();

    // every WG redundantly computes the identical verdict (no indexed arrays)
    int c0=0,c1=0,c2=0,c3=0,c4=0,c5=0,c6=0,c7=0, rank=0;
    bool bad = false;
    for (int j = 0; j < 256; ++j) {
        unsigned v = ldsx[j];
        bad = bad || (v > 7u);
        c0 += (v == 0u); c1 += (v == 1u); c2 += (v == 2u); c3 += (v == 3u);
        c4 += (v == 4u); c5 += (v == 5u); c6 += (v == 6u); c7 += (v == 7u);
        rank += (v == xcd && j < bid) ? 1 : 0;
    }
    const bool uni = !bad && c0==32 && c1==32 && c2==32 && c3==32 &&
                             c4==32 && c5==32 && c6==32 && c7==32;

    const int btile = uni ? (int)xcd : (bid & 7);
    const int hs    = uni ? rank      : (bid >> 3);

    // mfma identity: wave wg = gate wg; lane's B row / D col = hs*16 + (wl&15)
    const int wg = tid >> 6, wl = tid & 63;
    const int arow = wl & 15, kgrp = wl >> 4;
    const int grow = wg * 512 + hs * 16 + arow;

    f16x8 wh[16], wi[9];
    #pragma unroll
    for (int kc = 0; kc < 16; ++kc)
        wh[kc] = *(const f16x8*)(whh + (size_t)grow * 512 + kc * 32 + kgrp * 8);
    #pragma unroll
    for (int kc = 0; kc < 9; ++kc)
        wi[kc] = *(const f16x8*)(wih + (size_t)grow * 288 + kc * 32 + kgrp * 8);
    const float bb = bias[grow];

    unsigned* flags = cnt + 512 + btile * 32;

    if (uni)
        lstm_loop<1>(newx, hall, flags, wh, wi, bb, btile, hs, tid, gf);
    else
        lstm_loop<0>(newx, hall, flags, wh, wi, bb, btile, hs, tid, gf);
}

// ---------------- phase 3: out = sigmoid(h_all @ W_fc^T + b_fc) ----------------
__global__ void __launch_bounds__(256) out_gemm(const f16* __restrict__ hall,
                                                const f16* __restrict__ wfc,
                                                const float* __restrict__ bfc,
                                                float* __restrict__ out) {
    const int tid = threadIdx.x;
    const int w = tid >> 6, wl = tid & 63;
    const int arow = wl & 15, kgrp = wl >> 4;
    const long m0 = (long)blockIdx.x * 64 + w * 16;
    const f16* ap = hall + (m0 + arow) * 512 + kgrp * 8;
    f16x8 a[16];
    #pragma unroll
    for (int kc = 0; kc < 16; ++kc) a[kc] = *(const f16x8*)(ap + kc * 32);
    #pragma unroll
    for (int jt = 0; jt < 8; ++jt) {
        f32x4 acc = {0.f, 0.f, 0.f, 0.f};
        const f16* bp = wfc + (size_t)(jt * 16 + arow) * 512 + kgrp * 8;
        #pragma unroll
        for (int kc = 0; kc < 16; ++kc)
            acc = __builtin_amdgcn_mfma_f32_16x16x32_f16(a[kc], *(const f16x8*)(bp + kc * 32),
                                                         acc, 0, 0, 0);
        const int col = jt * 16 + arow;        // D col = lane&15
        if (col < 123) {
            const float bv = bfc[col];
            #pragma unroll
            for (int rr = 0; rr < 4; ++rr) {
                long m = m0 + kgrp * 4 + rr;   // D row = (lane>>4)*4 + reg
                int tt = (int)(m >> 7), b = (int)(m & 127);
                out[((size_t)b * 499 + tt) * 123 + col] = sigm_dev(acc[rr] + bv);
            }
        }
    }
}

extern "C" void kernel_launch(void* const* d_in, const int* in_sizes, int n_in,
                              void* d_out, int out_size, void* d_ws, size_t ws_size,
                              hipStream_t stream) {
    if (ws_size < WS_NEED) return;   // safe no-op rather than OOB writes

    const float* x    = (const float*)d_in[0];
    const float* W_ih = (const float*)d_in[1];
    const float* W_hh = (const float*)d_in[2];
    const float* b_ih = (const float*)d_in[3];
    const float* b_hh = (const float*)d_in[4];
    const float* W_fc = (const float*)d_in[5];
    const float* b_fc = (const float*)d_in[6];
    float* out = (float*)d_out;
    char* ws = (char*)d_ws;

    f16* newx   = (f16*)(ws + NEWX_OFF);
    f16* hall   = (f16*)(ws + HALL_OFF);
    f16* whh    = (f16*)(ws + WHH_OFF);
    f16* wih    = (f16*)(ws + WIH_OFF);
    f16* wfc    = (f16*)(ws + WFC_OFF);
    float* bias = (float*)(ws + BIAS_OFF);
    unsigned* cnt = (unsigned*)(ws + CNT_OFF);

    // counters/flags must be 0 at the start of every call (replays don't re-poison)
    hipMemsetAsync(cnt, 0, CNT_BYTES, stream);

    prep_newx<<<dim3(TS, 8), 256, 0, stream>>>(x, newx);
    prep_w<<<512, 256, 0, stream>>>(W_ih, W_hh, W_fc, b_ih, b_hh, whh, wih, wfc, bias);

    void* args[6] = {&newx, &hall, &whh, &wih, &bias, &cnt};
    hipLaunchCooperativeKernel((const void*)lstm_seq, dim3(256), dim3(256), args,
                               0, stream);

    out_gemm<<<998, 256, 0, stream>>>(hall, wfc, b_fc, out);
}